// Round 11
// baseline (434.178 us; speedup 1.0000x reference)
//
#include <hip/hip_runtime.h>
#include <stdint.h>

#define SEQN 16384
#define NBATCH 4

typedef __attribute__((ext_vector_type(8))) __bf16 bf16x8;
typedef __attribute__((ext_vector_type(4))) float f32x4;
typedef __attribute__((ext_vector_type(4))) unsigned int u32x4;

__device__ __forceinline__ unsigned int f2bf(float f) {
  unsigned int x = __builtin_bit_cast(unsigned int, f);
  x = x + 0x7fffu + ((x >> 16) & 1u);
  return x >> 16;
}
__device__ __forceinline__ float bf2f(unsigned int lo) {
  return __builtin_bit_cast(float, lo << 16);
}

__device__ __forceinline__ void gload_lds16(const unsigned short* g, unsigned char* l) {
  __builtin_amdgcn_global_load_lds(
      (const __attribute__((address_space(1))) unsigned int*)g,
      (__attribute__((address_space(3))) unsigned int*)l, 16, 0, 0);
}

// C = A @ Bt^T + bias.  A: [M][K] bf16 row-major, Bt: [Ncols][K] bf16 row-major.
// Proven m97-style 128x128 tile, BK=64, 4 waves (2x2), 2-barrier loop.
// LDS XOR-swizzle via pre-swizzled global source (rule #21), 0 loop conflicts.
// XCD-chunked block swizzle (T1). NOW 5 blocks/CU (LDS 5x32KB = 160KB exactly;
// VGPR 60 < 102 cap) for +25% drain-overlap waves.
// OUT_BF16 epilogue: LDS repack with (row>>2)*32 rotation — simultaneous
// quarter-wave row-groups (row delta 4) land in 4 disjoint 32B windows ->
// conflict-free ds_writes (old row*32 rotation was 4-way: 128*4 ≡ 0 mod 256).
template<bool OUT_BF16>
__global__ __launch_bounds__(256, 5)
void gemm_bt(const unsigned short* __restrict__ A,
             const unsigned short* __restrict__ Bt,
             const float* __restrict__ bias,
             void* __restrict__ Cout,
             int Ncols, int K)
{
  __shared__ __align__(16) unsigned char lds[32768];
  unsigned char* lA = lds;            // [128 rows][64 k] bf16 = 16 KiB
  unsigned char* lB = lds + 16384;    // [128 cols][64 k] bf16 = 16 KiB
  const int tid = threadIdx.x;
  const int lane = tid & 63;
  const int wid = tid >> 6;
  const int wr = (wid >> 1) * 64;   // wave row offset in tile
  const int wc = (wid & 1) * 64;    // wave col offset in tile
  const int nbx = Ncols >> 7;
  const int bid = (int)blockIdx.x;
  const int cpx = (int)gridDim.x >> 3;
  const int swz = (bid & 7) * cpx + (bid >> 3);
  const int bx = swz % nbx;
  const int by = swz / nbx;
  const long row0 = (long)by << 7;
  const int col0 = bx << 7;

  f32x4 acc[4][4];
#pragma unroll
  for (int i = 0; i < 4; ++i)
#pragma unroll
    for (int j = 0; j < 4; ++j) acc[i][j] = (f32x4)0.0f;

  for (int kt = 0; kt < K; kt += 64) {
#pragma unroll
    for (int i = 0; i < 4; ++i) {
      const int f = i * 256 + tid;          // 16B chunk index 0..1023
      const int r = f >> 3;                 // tile row 0..127
      const int cd = (f & 7) ^ (r & 7);     // inverse-swizzled source chunk
      gload_lds16(A + (row0 + r) * (long)K + kt + cd * 8, lA + f * 16);
      gload_lds16(Bt + (long)(col0 + r) * K + kt + cd * 8, lB + f * 16);
    }
    __syncthreads();
#pragma unroll
    for (int kk = 0; kk < 2; ++kk) {
      bf16x8 af[4], bfv[4];
#pragma unroll
      for (int fm = 0; fm < 4; ++fm) {
        const int row = wr + fm * 16 + (lane & 15);
        const int ch = (kk * 4 + (lane >> 4)) ^ (row & 7);
        af[fm] = __builtin_bit_cast(bf16x8, *(const u32x4*)(lA + row * 128 + ch * 16));
      }
#pragma unroll
      for (int fn = 0; fn < 4; ++fn) {
        const int row = wc + fn * 16 + (lane & 15);
        const int ch = (kk * 4 + (lane >> 4)) ^ (row & 7);
        bfv[fn] = __builtin_bit_cast(bf16x8, *(const u32x4*)(lB + row * 128 + ch * 16));
      }
#pragma unroll
      for (int fm = 0; fm < 4; ++fm)
#pragma unroll
        for (int fn = 0; fn < 4; ++fn)
          acc[fm][fn] = __builtin_amdgcn_mfma_f32_16x16x32_bf16(af[fm], bfv[fn], acc[fm][fn], 0, 0, 0);
    }
    __syncthreads();
  }

  if constexpr (OUT_BF16) {
    // Conflict-free repack: physical byte = row*256 + ((logical + (row>>2)*32) & 255).
#pragma unroll
    for (int fn = 0; fn < 4; ++fn) {
      const int n_loc = wc + fn * 16 + (lane & 15);
      const float bn = bias[col0 + n_loc];
#pragma unroll
      for (int fm = 0; fm < 4; ++fm) {
        const int rb = wr + fm * 16 + ((lane >> 4) << 2);
#pragma unroll
        for (int j = 0; j < 4; ++j) {
          const int row = rb + j;
          *(unsigned short*)(lds + row * 256 + ((n_loc * 2 + (row >> 2) * 32) & 255)) =
              (unsigned short)f2bf(acc[fm][fn][j] + bn);
        }
      }
    }
    __syncthreads();
    // 2048 16B chunks, 8/thread; consecutive tids -> consecutive 16B in a row
    // (rotation multiple of 32 -> no chunk straddle) -> coalesced 16B stores.
#pragma unroll
    for (int i = 0; i < 8; ++i) {
      const int chunk = i * 256 + tid;
      const int row = chunk >> 4;
      const int co = (chunk & 15) * 16;   // logical byte col
      const u32x4 v = *(const u32x4*)(lds + row * 256 + ((co + (row >> 2) * 32) & 255));
      *(u32x4*)((unsigned short*)Cout + (row0 + row) * (long)Ncols + col0 + (co >> 1)) = v;
    }
  } else {
#pragma unroll
    for (int fn = 0; fn < 4; ++fn) {
      const int n = col0 + wc + fn * 16 + (lane & 15);
      const float bn = bias[n];
#pragma unroll
      for (int fm = 0; fm < 4; ++fm) {
        const long mbase = row0 + wr + fm * 16 + ((lane >> 4) << 2);
#pragma unroll
        for (int j = 0; j < 4; ++j)
          ((float*)Cout)[(mbase + j) * (long)Ncols + n] = acc[fm][fn][j] + bn;
      }
    }
  }
}

// TWO query rows per wave (14 gathers in flight). qkv row: [q|k|v] bf16.
__global__ __launch_bounds__(256)
void nbr_attn(const unsigned short* __restrict__ qkv,
              const int* __restrict__ nbr,
              unsigned short* __restrict__ aout)
{
  const int w = (int)((blockIdx.x * 256 + threadIdx.x) >> 6);
  const int lane = threadIdx.x & 63;
  const int r0 = w * 2;
  const int n0 = r0 & (SEQN - 1);
  const int b  = r0 >> 14;

  const unsigned short* qr = qkv + (size_t)r0 * 1536;
  const u32x4 q0raw = *(const u32x4*)(qr + lane * 8);
  const u32x4 q1raw = *(const u32x4*)(qr + 1536 + lane * 8);

  int t[6];
  t[0] = nbr[n0];            t[3] = nbr[n0 + 1];
  t[1] = nbr[SEQN + n0];     t[4] = nbr[SEQN + n0 + 1];
  t[2] = nbr[2 * SEQN + n0]; t[5] = nbr[2 * SEQN + n0 + 1];

  const unsigned short* base = qkv + (size_t)b * SEQN * 1536 + 512 + lane * 8;
  u32x4 kr[6], vr[6];
#pragma unroll
  for (int k = 0; k < 6; ++k) {
    const unsigned short* p = base + (size_t)(t[k] > 0 ? t[k] : 0) * 1536;
    kr[k] = *(const u32x4*)p;
    vr[k] = *(const u32x4*)(p + 512);
  }

  float qv0[8], qv1[8];
#pragma unroll
  for (int i = 0; i < 4; ++i) {
    qv0[2 * i] = bf2f(q0raw[i] & 0xffffu);
    qv0[2 * i + 1] = bf2f(q0raw[i] >> 16);
    qv1[2 * i] = bf2f(q1raw[i] & 0xffffu);
    qv1[2 * i + 1] = bf2f(q1raw[i] >> 16);
  }

  float s[6];
#pragma unroll
  for (int k = 0; k < 6; ++k) {
    const float* q = (k < 3) ? qv0 : qv1;
    float d = 0.f;
#pragma unroll
    for (int i = 0; i < 4; ++i)
      d += q[2 * i] * bf2f(kr[k][i] & 0xffffu) + q[2 * i + 1] * bf2f(kr[k][i] >> 16);
    d += __shfl_xor(d, 1);
    d += __shfl_xor(d, 2);
    d += __shfl_xor(d, 4);
    s[k] = d * 0.125f;
  }

#pragma unroll
  for (int rrow = 0; rrow < 2; ++rrow) {
    const int o = rrow * 3;
    float m = -3.0e38f;
#pragma unroll
    for (int k = 0; k < 3; ++k)
      if (t[o + k] != -1) m = fmaxf(m, s[o + k]);
    float e[3], sum = 0.f;
#pragma unroll
    for (int k = 0; k < 3; ++k) {
      e[k] = (t[o + k] != -1) ? __expf(s[o + k] - m) : 0.f;
      sum += e[k];
    }
    const float inv = sum > 0.f ? 1.f / sum : 0.f;
    float acc[8] = {0.f, 0.f, 0.f, 0.f, 0.f, 0.f, 0.f, 0.f};
#pragma unroll
    for (int k = 0; k < 3; ++k) {
      const float wgt = e[k] * inv;
#pragma unroll
      for (int i = 0; i < 4; ++i) {
        acc[2 * i] += wgt * bf2f(vr[o + k][i] & 0xffffu);
        acc[2 * i + 1] += wgt * bf2f(vr[o + k][i] >> 16);
      }
    }
    u32x4 ov;
#pragma unroll
    for (int i = 0; i < 4; ++i)
      ov[i] = f2bf(acc[2 * i]) | (f2bf(acc[2 * i + 1]) << 16);
    *(u32x4*)(aout + (size_t)(r0 + rrow) * 512 + lane * 8) = ov;
  }
}

// Fused x f32->bf16 conversion + weight/bias prep (one dispatch).
__global__ __launch_bounds__(256)
void cvt_prep(const float* __restrict__ x, unsigned short* __restrict__ xb,
              const float* __restrict__ Wq, const float* __restrict__ Wk,
              const float* __restrict__ Wv, const float* __restrict__ Wo,
              const float* __restrict__ bq, const float* __restrict__ bk,
              const float* __restrict__ bv,
              unsigned short* __restrict__ wf, unsigned short* __restrict__ wo,
              float* __restrict__ biasf)
{
  const int i = blockIdx.x * 256 + threadIdx.x;
  if (i < 262144) {
    wf[i] = (unsigned short)f2bf(Wq[i]);
    wf[262144 + i] = (unsigned short)f2bf(Wk[i]);
    wf[524288 + i] = (unsigned short)f2bf(Wv[i]);
    wo[i] = (unsigned short)f2bf(Wo[i]);
  }
  if (i < 512) {
    biasf[i] = bq[i];
    biasf[512 + i] = bk[i];
    biasf[1024 + i] = bv[i];
  }
#pragma unroll
  for (int t = i; t < 4194304; t += 1048576) {
    const float4* p = (const float4*)(x + (size_t)t * 8);
    const float4 a = p[0], c = p[1];
    u32x4 o;
    o[0] = f2bf(a.x) | (f2bf(a.y) << 16);
    o[1] = f2bf(a.z) | (f2bf(a.w) << 16);
    o[2] = f2bf(c.x) | (f2bf(c.y) << 16);
    o[3] = f2bf(c.z) | (f2bf(c.w) << 16);
    *(u32x4*)(xb + (size_t)t * 8) = o;
  }
}

extern "C" void kernel_launch(void* const* d_in, const int* in_sizes, int n_in,
                              void* d_out, int out_size, void* d_ws, size_t ws_size,
                              hipStream_t stream) {
  const float* x  = (const float*)d_in[0];
  const int* nbr  = (const int*)d_in[1];
  const float* Wq = (const float*)d_in[2];
  const float* bq = (const float*)d_in[3];
  const float* Wk = (const float*)d_in[4];
  const float* bk = (const float*)d_in[5];
  const float* Wv = (const float*)d_in[6];
  const float* bv = (const float*)d_in[7];
  const float* Wo = (const float*)d_in[8];
  const float* bo = (const float*)d_in[9];
  float* out = (float*)d_out;
  unsigned char* ws = (unsigned char*)d_ws;

  // ws layout (bytes):
  //   [0, 64Mi)            x_bf16, later reused as attn_out_bf16 (65536*512*2)
  //   [64Mi, 256Mi)        qkv bf16 (65536*1536*2 = 192Mi)
  //   [256Mi, +1.5Mi)      fused W (Wq;Wk;Wv) bf16 [1536][512]
  //   [..., +0.5Mi)        Wo bf16 [512][512]
  //   [..., +6Ki)          fused bias f32 [1536]
  unsigned short* xb  = (unsigned short*)(ws);
  unsigned short* qkv = (unsigned short*)(ws + 67108864UL);
  unsigned short* wf  = (unsigned short*)(ws + 268435456UL);
  unsigned short* wo  = (unsigned short*)(ws + 270008320UL);
  float* biasf        = (float*)(ws + 270532608UL);

  cvt_prep<<<4096, 256, 0, stream>>>(x, xb, Wq, Wk, Wv, Wo, bq, bk, bv, wf, wo, biasf);
  // QKV projection: M=65536, N=1536, K=512
  gemm_bt<true><<<dim3(512 * 12), 256, 0, stream>>>(xb, wf, biasf, qkv, 1536, 512);
  // neighbor attention (2 rows/wave; reuses xb region for output)
  nbr_attn<<<8192, 256, 0, stream>>>(qkv, nbr, xb);
  // output projection: M=65536, N=512, K=512, f32 out
  gemm_bt<false><<<dim3(512 * 4), 256, 0, stream>>>(xb, wo, bo, out, 512, 512);
}

// Round 12
// 279.841 us; speedup vs baseline: 1.5515x; 1.5515x over previous
//
#include <hip/hip_runtime.h>
#include <stdint.h>

#define SEQN 16384
#define NBATCH 4

typedef __attribute__((ext_vector_type(8))) __bf16 bf16x8;
typedef __attribute__((ext_vector_type(4))) float f32x4;
typedef __attribute__((ext_vector_type(4))) unsigned int u32x4;

__device__ __forceinline__ unsigned int f2bf(float f) {
  unsigned int x = __builtin_bit_cast(unsigned int, f);
  x = x + 0x7fffu + ((x >> 16) & 1u);
  return x >> 16;
}
__device__ __forceinline__ float bf2f(unsigned int lo) {
  return __builtin_bit_cast(float, lo << 16);
}

__device__ __forceinline__ void gload_lds16(const unsigned short* g, unsigned char* l) {
  __builtin_amdgcn_global_load_lds(
      (const __attribute__((address_space(1))) unsigned int*)g,
      (__attribute__((address_space(3))) unsigned int*)l, 16, 0, 0);
}

// C = A @ Bt^T + bias.  A: [M][K] bf16 row-major, Bt: [Ncols][K] bf16 row-major.
// Proven m97-style 128x128 tile, BK=64, 4 waves (2x2), 2-barrier loop.
// __launch_bounds__(256,4): VGPR 64, no spill (R11's (256,5) capped VGPR at 48
// -> acc spilled to scratch, 2x regression — do NOT raise).
// LDS XOR-swizzle via pre-swizzled global source (rule #21), 0 loop conflicts.
// XCD-chunked block swizzle (T1, gridDim%8==0 -> bijective).
// OUT_BF16 epilogue: LDS repack with (row>>2)*32 rotation — simultaneous
// quarter-wave row-groups (row delta 4) land in 4 disjoint 32B windows ->
// conflict-free ds_writes (R9's row*32 rotation measured 3.9M conflicts).
template<bool OUT_BF16>
__global__ __launch_bounds__(256, 4)
void gemm_bt(const unsigned short* __restrict__ A,
             const unsigned short* __restrict__ Bt,
             const float* __restrict__ bias,
             void* __restrict__ Cout,
             int Ncols, int K)
{
  __shared__ __align__(16) unsigned char lds[32768];
  unsigned char* lA = lds;            // [128 rows][64 k] bf16 = 16 KiB
  unsigned char* lB = lds + 16384;    // [128 cols][64 k] bf16 = 16 KiB
  const int tid = threadIdx.x;
  const int lane = tid & 63;
  const int wid = tid >> 6;
  const int wr = (wid >> 1) * 64;   // wave row offset in tile
  const int wc = (wid & 1) * 64;    // wave col offset in tile
  const int nbx = Ncols >> 7;
  const int bid = (int)blockIdx.x;
  const int cpx = (int)gridDim.x >> 3;
  const int swz = (bid & 7) * cpx + (bid >> 3);
  const int bx = swz % nbx;
  const int by = swz / nbx;
  const long row0 = (long)by << 7;
  const int col0 = bx << 7;

  f32x4 acc[4][4];
#pragma unroll
  for (int i = 0; i < 4; ++i)
#pragma unroll
    for (int j = 0; j < 4; ++j) acc[i][j] = (f32x4)0.0f;

  for (int kt = 0; kt < K; kt += 64) {
#pragma unroll
    for (int i = 0; i < 4; ++i) {
      const int f = i * 256 + tid;          // 16B chunk index 0..1023
      const int r = f >> 3;                 // tile row 0..127
      const int cd = (f & 7) ^ (r & 7);     // inverse-swizzled source chunk
      gload_lds16(A + (row0 + r) * (long)K + kt + cd * 8, lA + f * 16);
      gload_lds16(Bt + (long)(col0 + r) * K + kt + cd * 8, lB + f * 16);
    }
    __syncthreads();
#pragma unroll
    for (int kk = 0; kk < 2; ++kk) {
      bf16x8 af[4], bfv[4];
#pragma unroll
      for (int fm = 0; fm < 4; ++fm) {
        const int row = wr + fm * 16 + (lane & 15);
        const int ch = (kk * 4 + (lane >> 4)) ^ (row & 7);
        af[fm] = __builtin_bit_cast(bf16x8, *(const u32x4*)(lA + row * 128 + ch * 16));
      }
#pragma unroll
      for (int fn = 0; fn < 4; ++fn) {
        const int row = wc + fn * 16 + (lane & 15);
        const int ch = (kk * 4 + (lane >> 4)) ^ (row & 7);
        bfv[fn] = __builtin_bit_cast(bf16x8, *(const u32x4*)(lB + row * 128 + ch * 16));
      }
#pragma unroll
      for (int fm = 0; fm < 4; ++fm)
#pragma unroll
        for (int fn = 0; fn < 4; ++fn)
          acc[fm][fn] = __builtin_amdgcn_mfma_f32_16x16x32_bf16(af[fm], bfv[fn], acc[fm][fn], 0, 0, 0);
    }
    __syncthreads();
  }

  if constexpr (OUT_BF16) {
    // Conflict-free repack: physical byte = row*256 + ((logical + (row>>2)*32) & 255).
#pragma unroll
    for (int fn = 0; fn < 4; ++fn) {
      const int n_loc = wc + fn * 16 + (lane & 15);
      const float bn = bias[col0 + n_loc];
#pragma unroll
      for (int fm = 0; fm < 4; ++fm) {
        const int rb = wr + fm * 16 + ((lane >> 4) << 2);
#pragma unroll
        for (int j = 0; j < 4; ++j) {
          const int row = rb + j;
          *(unsigned short*)(lds + row * 256 + ((n_loc * 2 + (row >> 2) * 32) & 255)) =
              (unsigned short)f2bf(acc[fm][fn][j] + bn);
        }
      }
    }
    __syncthreads();
    // 2048 16B chunks, 8/thread; consecutive tids -> consecutive 16B in a row
    // (rotation multiple of 32 -> no chunk straddle) -> coalesced 16B stores.
#pragma unroll
    for (int i = 0; i < 8; ++i) {
      const int chunk = i * 256 + tid;
      const int row = chunk >> 4;
      const int co = (chunk & 15) * 16;   // logical byte col
      const u32x4 v = *(const u32x4*)(lds + row * 256 + ((co + (row >> 2) * 32) & 255));
      *(u32x4*)((unsigned short*)Cout + (row0 + row) * (long)Ncols + col0 + (co >> 1)) = v;
    }
  } else {
#pragma unroll
    for (int fn = 0; fn < 4; ++fn) {
      const int n = col0 + wc + fn * 16 + (lane & 15);
      const float bn = bias[n];
#pragma unroll
      for (int fm = 0; fm < 4; ++fm) {
        const long mbase = row0 + wr + fm * 16 + ((lane >> 4) << 2);
#pragma unroll
        for (int j = 0; j < 4; ++j)
          ((float*)Cout)[(mbase + j) * (long)Ncols + n] = acc[fm][fn][j] + bn;
      }
    }
  }
}

// TWO query rows per wave (14 gathers in flight). qkv row: [q|k|v] bf16.
__global__ __launch_bounds__(256)
void nbr_attn(const unsigned short* __restrict__ qkv,
              const int* __restrict__ nbr,
              unsigned short* __restrict__ aout)
{
  const int w = (int)((blockIdx.x * 256 + threadIdx.x) >> 6);
  const int lane = threadIdx.x & 63;
  const int r0 = w * 2;
  const int n0 = r0 & (SEQN - 1);
  const int b  = r0 >> 14;

  const unsigned short* qr = qkv + (size_t)r0 * 1536;
  const u32x4 q0raw = *(const u32x4*)(qr + lane * 8);
  const u32x4 q1raw = *(const u32x4*)(qr + 1536 + lane * 8);

  int t[6];
  t[0] = nbr[n0];            t[3] = nbr[n0 + 1];
  t[1] = nbr[SEQN + n0];     t[4] = nbr[SEQN + n0 + 1];
  t[2] = nbr[2 * SEQN + n0]; t[5] = nbr[2 * SEQN + n0 + 1];

  const unsigned short* base = qkv + (size_t)b * SEQN * 1536 + 512 + lane * 8;
  u32x4 kr[6], vr[6];
#pragma unroll
  for (int k = 0; k < 6; ++k) {
    const unsigned short* p = base + (size_t)(t[k] > 0 ? t[k] : 0) * 1536;
    kr[k] = *(const u32x4*)p;
    vr[k] = *(const u32x4*)(p + 512);
  }

  float qv0[8], qv1[8];
#pragma unroll
  for (int i = 0; i < 4; ++i) {
    qv0[2 * i] = bf2f(q0raw[i] & 0xffffu);
    qv0[2 * i + 1] = bf2f(q0raw[i] >> 16);
    qv1[2 * i] = bf2f(q1raw[i] & 0xffffu);
    qv1[2 * i + 1] = bf2f(q1raw[i] >> 16);
  }

  float s[6];
#pragma unroll
  for (int k = 0; k < 6; ++k) {
    const float* q = (k < 3) ? qv0 : qv1;
    float d = 0.f;
#pragma unroll
    for (int i = 0; i < 4; ++i)
      d += q[2 * i] * bf2f(kr[k][i] & 0xffffu) + q[2 * i + 1] * bf2f(kr[k][i] >> 16);
    d += __shfl_xor(d, 1);
    d += __shfl_xor(d, 2);
    d += __shfl_xor(d, 4);
    s[k] = d * 0.125f;
  }

#pragma unroll
  for (int rrow = 0; rrow < 2; ++rrow) {
    const int o = rrow * 3;
    float m = -3.0e38f;
#pragma unroll
    for (int k = 0; k < 3; ++k)
      if (t[o + k] != -1) m = fmaxf(m, s[o + k]);
    float e[3], sum = 0.f;
#pragma unroll
    for (int k = 0; k < 3; ++k) {
      e[k] = (t[o + k] != -1) ? __expf(s[o + k] - m) : 0.f;
      sum += e[k];
    }
    const float inv = sum > 0.f ? 1.f / sum : 0.f;
    float acc[8] = {0.f, 0.f, 0.f, 0.f, 0.f, 0.f, 0.f, 0.f};
#pragma unroll
    for (int k = 0; k < 3; ++k) {
      const float wgt = e[k] * inv;
#pragma unroll
      for (int i = 0; i < 4; ++i) {
        acc[2 * i] += wgt * bf2f(vr[o + k][i] & 0xffffu);
        acc[2 * i + 1] += wgt * bf2f(vr[o + k][i] >> 16);
      }
    }
    u32x4 ov;
#pragma unroll
    for (int i = 0; i < 4; ++i)
      ov[i] = f2bf(acc[2 * i]) | (f2bf(acc[2 * i + 1]) << 16);
    *(u32x4*)(aout + (size_t)(r0 + rrow) * 512 + lane * 8) = ov;
  }
}

// Fused x f32->bf16 conversion + weight/bias prep (one dispatch).
__global__ __launch_bounds__(256)
void cvt_prep(const float* __restrict__ x, unsigned short* __restrict__ xb,
              const float* __restrict__ Wq, const float* __restrict__ Wk,
              const float* __restrict__ Wv, const float* __restrict__ Wo,
              const float* __restrict__ bq, const float* __restrict__ bk,
              const float* __restrict__ bv,
              unsigned short* __restrict__ wf, unsigned short* __restrict__ wo,
              float* __restrict__ biasf)
{
  const int i = blockIdx.x * 256 + threadIdx.x;
  if (i < 262144) {
    wf[i] = (unsigned short)f2bf(Wq[i]);
    wf[262144 + i] = (unsigned short)f2bf(Wk[i]);
    wf[524288 + i] = (unsigned short)f2bf(Wv[i]);
    wo[i] = (unsigned short)f2bf(Wo[i]);
  }
  if (i < 512) {
    biasf[i] = bq[i];
    biasf[512 + i] = bk[i];
    biasf[1024 + i] = bv[i];
  }
#pragma unroll
  for (int t = i; t < 4194304; t += 1048576) {
    const float4* p = (const float4*)(x + (size_t)t * 8);
    const float4 a = p[0], c = p[1];
    u32x4 o;
    o[0] = f2bf(a.x) | (f2bf(a.y) << 16);
    o[1] = f2bf(a.z) | (f2bf(a.w) << 16);
    o[2] = f2bf(c.x) | (f2bf(c.y) << 16);
    o[3] = f2bf(c.z) | (f2bf(c.w) << 16);
    *(u32x4*)(xb + (size_t)t * 8) = o;
  }
}

extern "C" void kernel_launch(void* const* d_in, const int* in_sizes, int n_in,
                              void* d_out, int out_size, void* d_ws, size_t ws_size,
                              hipStream_t stream) {
  const float* x  = (const float*)d_in[0];
  const int* nbr  = (const int*)d_in[1];
  const float* Wq = (const float*)d_in[2];
  const float* bq = (const float*)d_in[3];
  const float* Wk = (const float*)d_in[4];
  const float* bk = (const float*)d_in[5];
  const float* Wv = (const float*)d_in[6];
  const float* bv = (const float*)d_in[7];
  const float* Wo = (const float*)d_in[8];
  const float* bo = (const float*)d_in[9];
  float* out = (float*)d_out;
  unsigned char* ws = (unsigned char*)d_ws;

  // ws layout (bytes):
  //   [0, 64Mi)            x_bf16, later reused as attn_out_bf16 (65536*512*2)
  //   [64Mi, 256Mi)        qkv bf16 (65536*1536*2 = 192Mi)
  //   [256Mi, +1.5Mi)      fused W (Wq;Wk;Wv) bf16 [1536][512]
  //   [..., +0.5Mi)        Wo bf16 [512][512]
  //   [..., +6Ki)          fused bias f32 [1536]
  unsigned short* xb  = (unsigned short*)(ws);
  unsigned short* qkv = (unsigned short*)(ws + 67108864UL);
  unsigned short* wf  = (unsigned short*)(ws + 268435456UL);
  unsigned short* wo  = (unsigned short*)(ws + 270008320UL);
  float* biasf        = (float*)(ws + 270532608UL);

  cvt_prep<<<4096, 256, 0, stream>>>(x, xb, Wq, Wk, Wv, Wo, bq, bk, bv, wf, wo, biasf);
  // QKV projection: M=65536, N=1536, K=512
  gemm_bt<true><<<dim3(512 * 12), 256, 0, stream>>>(xb, wf, biasf, qkv, 1536, 512);
  // neighbor attention (2 rows/wave; reuses xb region for output)
  nbr_attn<<<8192, 256, 0, stream>>>(qkv, nbr, xb);
  // output projection: M=65536, N=512, K=512, f32 out
  gemm_bt<false><<<dim3(512 * 4), 256, 0, stream>>>(xb, wo, bo, out, 512, 512);
}